// Round 4
// baseline (381.575 us; speedup 1.0000x reference)
//
#include <hip/hip_runtime.h>

// AdaptiveGraphConvolution on MI355X — round 4: kill scalar LDS-transpose staging.
// N=64, C=64, T=300, V=25, S=3 subsets, IC=16, O=64.
//
// k0 (NEW): pre-pack a_w/b_w into MFMA A-operand bf16 layout wpk[rt][s][lane][8]
//   so k1 waves load W-frags as 12 dwordx4 (no W LDS, no W staging barrier).
// k1 (restructured): stage x NATURALLY [c][tv 0..299] bf16 (float4 reads, packed
//   b32 writes, stride 306 -> odd dword-stride 153: B-frag quad reads land on
//   disjoint bank groups). Phase A B-frags via 16 ds_read_u16/tile (transpose
//   eaten at read time, reused across 6 r-tiles). Phase B / reduce / atomics
//   verbatim from round 3 (validated).
// k2 (unchanged): softmax + atT/gwb prep.
// k3 (staging fixed): packed-pair b32 LDS writes instead of 8000 ds_write_b16.

#define NB 64
#define CB 64
#define TB 300
#define VB 25

typedef unsigned int uint32;
typedef unsigned short ushort16;
typedef __attribute__((ext_vector_type(8))) short short8;
typedef __attribute__((ext_vector_type(4))) float f32x4;
typedef __attribute__((ext_vector_type(16))) float f32x16;
typedef __attribute__((ext_vector_type(4))) uint32 u32x4;

__device__ __forceinline__ ushort16 f2bf(float f) {
    uint32 u = __float_as_uint(f);
    u = u + 0x7FFFu + ((u >> 16) & 1u);
    return (ushort16)(u >> 16);
}
__device__ __forceinline__ float bf2f(ushort16 h) {
    return __uint_as_float(((uint32)h) << 16);
}
__device__ __forceinline__ uint32 packbf2(float a, float b) {
    return (uint32)f2bf(a) | ((uint32)f2bf(b) << 16);
}

// ---------------------------------------------------------------- kernel 0
// pack W (a_w rows 0..47, b_w rows 48..95) into A-frag layout:
// wpk u32[(rt*2+s)*256 + lane*4 + p] = bf16 pair W[r][c], W[r][c+1]
// with r = rt*16 + (lane&15), c = s*32 + (lane>>4)*8 + 2p.
__global__ __launch_bounds__(256) void k0_pack_w(
    const float* __restrict__ a_w, const float* __restrict__ b_w,
    uint32* __restrict__ wpk)
{
    int idx = blockIdx.x * 256 + threadIdx.x;
    if (idx < 3072) {
        int s12 = idx >> 8, rem = idx & 255;
        int lane = rem >> 2, p = rem & 3;
        int r = (s12 >> 1) * 16 + (lane & 15);
        int c = (s12 & 1) * 32 + (lane >> 4) * 8 + 2 * p;
        const float* row = (r < 48) ? (a_w + r * 64) : (b_w + (r - 48) * 64);
        wpk[idx] = packbf2(row[c], row[c + 1]);
    }
}

// ---------------------------------------------------------------- kernel 1
// grid 1600 = 64 n * 25 chunks (12 t), 256 thr = 4 waves
__global__ __launch_bounds__(256) void k1_attn_logits_mfma(
    const float* __restrict__ x, const uint32* __restrict__ wpk,
    const float* __restrict__ a_b, const float* __restrict__ b_b,
    float* __restrict__ Mb)
{
    __shared__ ushort16 slab[64 * 306];  // x bf16 [c][tv 0..299], stride 306
    __shared__ ushort16 abT[192 * 64];   // [g*32+v][k=(tl,ic)] bf16, swizzled
    __shared__ __align__(16) float bias[96];

    const int tid   = threadIdx.x;
    const int n     = blockIdx.x / 25;
    const int chunk = blockIdx.x % 25;
    const float* xn = x + n * (CB * TB * VB) + chunk * 300;  // c-stride 7500

    // ---- stage whole 12-t slab: 19200 floats, vectorized + packed writes
    for (int idx = tid; idx < 4800; idx += 256) {
        int c = idx / 75, g = idx % 75;
        float4 v4 = *(const float4*)(xn + c * 7500 + g * 4);
        uint32* d = (uint32*)&slab[c * 306 + g * 4];
        d[0] = packbf2(v4.x, v4.y);
        d[1] = packbf2(v4.z, v4.w);
    }
    for (int idx = tid; idx < 96; idx += 256)
        bias[idx] = (idx < 48) ? a_b[idx] : b_b[idx - 48];

    const int w    = tid >> 6;
    const int lane = tid & 63;
    const int l15  = lane & 15;
    const int q    = lane >> 4;
    const int hi   = lane >> 5;
    const int v32  = lane & 31;

    // ---- preload W A-frags (12 dwordx4, L1/L2-hot across all blocks)
    short8 gfW[12];
    #pragma unroll
    for (int s12 = 0; s12 < 12; ++s12)
        gfW[s12] = ((const short8*)wpk)[s12 * 64 + lane];

    f32x16 acc[3];
    #pragma unroll
    for (int i = 0; i < 3; ++i)
        #pragma unroll
        for (int r = 0; r < 16; ++r) acc[i][r] = 0.f;
    const f32x4 zf = (f32x4){0.f, 0.f, 0.f, 0.f};

    __syncthreads();

    for (int s = 0; s < 3; ++s) {
        if (s) __syncthreads();   // previous iter's abT consumers done
        // ---- phase A: ab = W @ x; B-frags read-transposed from natural slab
        for (int ct = w; ct < 7; ct += 4) {
            int tvL = ct * 16 + l15;               // local col in [0,112)
            int tvc = s * 100 + tvL;
            if (tvc > 299) tvc = 299;              // clamped reads, discarded
            u32x4 b0v, b1v;
            #pragma unroll
            for (int p = 0; p < 4; ++p) {
                int c0 = q * 8 + 2 * p;
                b0v[p] = (uint32)slab[c0 * 306 + tvc] |
                         ((uint32)slab[(c0 + 1) * 306 + tvc] << 16);
                b1v[p] = (uint32)slab[(c0 + 32) * 306 + tvc] |
                         ((uint32)slab[(c0 + 33) * 306 + tvc] << 16);
            }
            short8 bf0 = __builtin_bit_cast(short8, b0v);
            short8 bf1 = __builtin_bit_cast(short8, b1v);
            #pragma unroll
            for (int rt = 0; rt < 6; ++rt) {
                f32x4 d = zf;
                d = __builtin_amdgcn_mfma_f32_16x16x32_bf16(gfW[rt * 2], bf0, d, 0, 0, 0);
                d = __builtin_amdgcn_mfma_f32_16x16x32_bf16(gfW[rt * 2 + 1], bf1, d, 0, 0, 0);
                if (tvL < 100) {
                    float4 bi = *(const float4*)&bias[rt * 16 + q * 4];
                    int tl = tvL / 25, v = tvL % 25;
                    int kb = tl * 2 + (q >> 1);
                    uint32* dst = (uint32*)&abT[(rt * 32 + v) * 64 +
                                                (((kb + v) & 7) << 3) + ((q & 1) << 2)];
                    dst[0] = packbf2(d[0] + bi.x, d[1] + bi.y);
                    dst[1] = packbf2(d[2] + bi.z, d[3] + bi.w);
                }
            }
        }
        __syncthreads();
        // ---- phase B: wave w owns local t = w; M_i += a_i^T b_i
        {
            int kb = w * 2 + hi;
            #pragma unroll
            for (int i = 0; i < 3; ++i) {
                short8 af = *(const short8*)&abT[(i * 32 + v32) * 64 +
                                                 (((kb + v32) & 7) << 3)];
                short8 bf = *(const short8*)&abT[((3 + i) * 32 + v32) * 64 +
                                                 (((kb + v32) & 7) << 3)];
                acc[i] = __builtin_amdgcn_mfma_f32_32x32x16_bf16(af, bf, acc[i], 0, 0, 0);
            }
        }
    }

    // ---- cross-wave reduction in LDS (reuse slab region), then atomics
    float* Ms = (float*)slab;   // [3][32][33] f32 = 12672 B
    __syncthreads();
    for (int idx = tid; idx < 3 * 32 * 33; idx += 256) Ms[idx] = 0.f;
    __syncthreads();
    for (int wv = 0; wv < 4; ++wv) {
        if (w == wv) {
            #pragma unroll
            for (int i = 0; i < 3; ++i)
                #pragma unroll
                for (int r = 0; r < 16; ++r) {
                    int row = (r & 3) + 8 * (r >> 2) + 4 * hi;   // 32x32 C-layout
                    Ms[i * 1056 + row * 33 + v32] += acc[i][r];
                }
        }
        __syncthreads();
    }
    const float inv = 1.0f / 4800.0f;
    for (int idx = tid; idx < 1875; idx += 256) {
        int i = idx / 625, rem = idx % 625;
        int v1 = rem / 25, v2 = rem % 25;
        atomicAdd(Mb + ((i * NB + n) * 25 + v1) * 25 + v2,
                  Ms[i * 1056 + v1 * 33 + v2] * inv);
    }
}

// ---------------------------------------------------------------- kernel 2
// softmax over v1 per (i,n,v2) + A_tot -> atT bf16 [i][n][v2][v1 pad32]
// plus g_w -> gw_bf bf16 [o][k=i*64+c] (A-operand layout for k3)
__global__ __launch_bounds__(256) void k2_softmax_prep(
    const float* __restrict__ Mb, const float* __restrict__ A,
    const float* __restrict__ GA, const float* __restrict__ g_w,
    uint32* __restrict__ atT, uint32* __restrict__ gwb)
{
    int idx = blockIdx.x * 256 + threadIdx.x;
    if (idx < 4800) {
        int v2 = idx % 25, n = (idx / 25) % 64, i = idx / 1600;
        const float* mcol = Mb + ((i * 64 + n) * 25) * 25 + v2;
        float e[25], mx = -1e30f;
        #pragma unroll
        for (int v1 = 0; v1 < 25; ++v1) { e[v1] = mcol[v1 * 25]; mx = fmaxf(mx, e[v1]); }
        float s = 0.f;
        #pragma unroll
        for (int v1 = 0; v1 < 25; ++v1) { e[v1] = __expf(e[v1] - mx); s += e[v1]; }
        float invs = 1.0f / s;
        const float* acol = A + i * 625 + v2;
        const float* gcol = GA + i * 625 + v2;
        float w[25];
        #pragma unroll
        for (int v1 = 0; v1 < 25; ++v1)
            w[v1] = e[v1] * invs + acol[v1 * 25] + gcol[v1 * 25];
        uint32* row = atT + ((i * 64 + n) * 32 + v2) * 16;
        #pragma unroll
        for (int p = 0; p < 12; ++p) row[p] = packbf2(w[2 * p], w[2 * p + 1]);
        row[12] = (uint32)f2bf(w[24]);
        row[13] = 0u; row[14] = 0u; row[15] = 0u;
    } else if (idx < 4800 + 6144) {
        int j = idx - 4800;
        int o = j / 96, kp = j % 96;
        int k0 = 2 * kp;
        int i = k0 >> 6, c = k0 & 63;
        float lo = g_w[(i * 64 + o) * 64 + c];
        float hi = g_w[(i * 64 + o) * 64 + c + 1];
        gwb[o * 96 + kp] = packbf2(lo, hi);
    }
}

// ---------------------------------------------------------------- kernel 3
// MFMA. grid 3840 = 64 n * 60 chunks of 5 t; 256 thr = 4 waves (wave=o/c tile)
__global__ __launch_bounds__(256) void k3_out(
    const float* __restrict__ x, const uint32* __restrict__ atT,
    const ushort16* __restrict__ gwb, const float* __restrict__ g_b,
    const float* __restrict__ bn_g, const float* __restrict__ bn_b,
    const float* __restrict__ bn_m, const float* __restrict__ bn_v,
    float* __restrict__ out)
{
    __shared__ ushort16 xs[64 * 168];   // [c][t*32 + v1]  (stride 168: 2-way banks)
    __shared__ uint32  xa[128 * 36];    // [col=(t,v2) pad128][c: 72 bf16 as 36 u32]
    __shared__ uint32  ats[3 * 32 * 20];// [i][v2][v1: 40 bf16 as 20 u32]
    __shared__ float   bsc[64], bsh[64];

    const int tid = threadIdx.x;
    const int n  = blockIdx.x / 60;
    const int t0 = (blockIdx.x % 60) * 5;

    // ---- stage x tile -> bf16 [c][t*32+v], packed-pair writes (incl. zero pad)
    for (int idx = tid; idx < 2240; idx += 256) {
        int c = idx / 35, r = idx % 35;
        int t = r / 7, g = r % 7;
        const float* src = x + ((n * 64 + c) * 300 + t0 + t) * 25;
        uint32* drow = (uint32*)&xs[c * 168 + t * 32];
        if (g < 6) {
            float a0 = src[g * 4 + 0], a1 = src[g * 4 + 1];
            float a2 = src[g * 4 + 2], a3 = src[g * 4 + 3];
            drow[g * 2]     = packbf2(a0, a1);
            drow[g * 2 + 1] = packbf2(a2, a3);
        } else {
            drow[12] = (uint32)f2bf(src[24]);
            drow[13] = 0u; drow[14] = 0u; drow[15] = 0u;
        }
    }
    // stage attn^T rows for this n
    for (int idx = tid; idx < 1536; idx += 256) {
        int row = idx >> 4, d = idx & 15;   // row = i*32+v2
        ats[row * 20 + d] = atT[((row >> 5) * 64 + n) * 512 + (row & 31) * 16 + d];
    }
    // BN scale/shift prefold (h = acc*sc + sh + x)
    for (int idx = tid; idx < 64; idx += 256) {
        float sc = bn_g[idx] * rsqrtf(bn_v[idx] + 1e-5f);
        bsc[idx] = sc;
        bsh[idx] = (g_b[idx] + g_b[64 + idx] + g_b[128 + idx] - bn_m[idx]) * sc + bn_b[idx];
    }
    // zero xa pad rows (cols 125..127)
    for (int idx = tid; idx < 3 * 36; idx += 256)
        xa[(125 + idx / 36) * 36 + idx % 36] = 0u;

    const int w    = tid >> 6;      // wave id = o-tile (main) = c-tile (xa)
    const int lane = tid & 63;
    const int l15  = lane & 15;
    const int q    = lane >> 4;

    // preload A-frags of gw (all 6 K-steps: k = i*64 + s*32)
    short8 gf[6];
    #pragma unroll
    for (int s = 0; s < 6; ++s)
        gf[s] = *(const short8*)(gwb + ((w * 16 + l15) * 192 + s * 32 + q * 8));

    f32x4 acc[8];
    #pragma unroll
    for (int ct = 0; ct < 8; ++ct) acc[ct] = (f32x4){0.f, 0.f, 0.f, 0.f};
    const f32x4 zf = (f32x4){0.f, 0.f, 0.f, 0.f};

    __syncthreads();

    for (int i = 0; i < 3; ++i) {
        if (i) __syncthreads();   // previous xa fully consumed
        // ---- xa-phase: this wave produces c-rows [w*16, w*16+16)
        #pragma unroll
        for (int t = 0; t < 5; ++t) {
            short8 ax = *(const short8*)(xs + (w * 16 + l15) * 168 + t * 32 + q * 8);
            #pragma unroll
            for (int vt = 0; vt < 2; ++vt) {
                short8 bt = *(const short8*)((const ushort16*)ats +
                                             (i * 32 + vt * 16 + l15) * 40 + q * 8);
                f32x4 d = __builtin_amdgcn_mfma_f32_16x16x32_bf16(ax, bt, zf, 0, 0, 0);
                int v2 = vt * 16 + l15;
                if (v2 < 25) {
                    int col = t * 25 + v2;
                    int c0  = w * 16 + q * 4;
                    xa[col * 36 + (c0 >> 1)]     = packbf2(d[0], d[1]);
                    xa[col * 36 + (c0 >> 1) + 1] = packbf2(d[2], d[3]);
                }
            }
        }
        __syncthreads();
        // ---- main GEMM: acc[o,col] += gw_i[o,c] * xa[c,col]
        #pragma unroll
        for (int ct = 0; ct < 8; ++ct) {
            #pragma unroll
            for (int s = 0; s < 2; ++s) {
                short8 bfrag = *(const short8*)((const ushort16*)xa +
                                                (ct * 16 + l15) * 72 + s * 32 + q * 8);
                acc[ct] = __builtin_amdgcn_mfma_f32_16x16x32_bf16(
                    gf[i * 2 + s], bfrag, acc[ct], 0, 0, 0);
            }
        }
    }

    // ---- epilogue: BN + residual (bf16 xs) + relu, direct coalesced store
    const int o0 = w * 16 + q * 4;
    #pragma unroll
    for (int ct = 0; ct < 8; ++ct) {
        int col = ct * 16 + l15;
        if (col < 125) {
            int tl = col / 25;
            int v  = col - tl * 25;
            float* ob = out + (n * 64 + o0) * 7500 + t0 * 25 + col;
            #pragma unroll
            for (int r = 0; r < 4; ++r) {
                int o = o0 + r;
                float xv = bf2f(xs[o * 168 + tl * 32 + v]);
                float h = acc[ct][r] * bsc[o] + bsh[o] + xv;
                ob[r * 7500] = fmaxf(h, 0.f);
            }
        }
    }
}

// ---------------------------------------------------------------- launch
extern "C" void kernel_launch(void* const* d_in, const int* in_sizes, int n_in,
                              void* d_out, int out_size, void* d_ws, size_t ws_size,
                              hipStream_t stream) {
    const float* x    = (const float*)d_in[0];
    const float* A    = (const float*)d_in[1];
    const float* GA   = (const float*)d_in[2];
    const float* g_w  = (const float*)d_in[3];
    const float* g_b  = (const float*)d_in[4];
    const float* a_w  = (const float*)d_in[5];
    const float* a_b  = (const float*)d_in[6];
    const float* b_w  = (const float*)d_in[7];
    const float* b_b  = (const float*)d_in[8];
    const float* bn_g = (const float*)d_in[9];
    const float* bn_b = (const float*)d_in[10];
    const float* bn_m = (const float*)d_in[11];
    const float* bn_v = (const float*)d_in[12];
    float* out = (float*)d_out;

    // ws: Mb f32[120000] (480000 B) | atT bf16 (393216 B) | gwb (24576 B)
    // wpk (12288 B) ALIASES the atT region: consumed by k1 before k2 writes atT.
    float*  Mb  = (float*)d_ws;
    uint32* atT = (uint32*)((char*)d_ws + 480000);
    uint32* gwb = (uint32*)((char*)d_ws + 480000 + 393216);
    uint32* wpk = atT;

    hipMemsetAsync(d_ws, 0, 480000, stream);  // zero M accumulators
    k0_pack_w<<<dim3(12), dim3(256), 0, stream>>>(a_w, b_w, wpk);
    k1_attn_logits_mfma<<<dim3(1600), dim3(256), 0, stream>>>(x, wpk, a_b, b_b, Mb);
    k2_softmax_prep<<<dim3(43), dim3(256), 0, stream>>>(Mb, A, GA, g_w, atT, gwb);
    k3_out<<<dim3(3840), dim3(256), 0, stream>>>(x, atT, (const ushort16*)gwb,
                                                 g_b, bn_g, bn_b, bn_m, bn_v, out);
}